// Round 1
// baseline (172.212 us; speedup 1.0000x reference)
//
#include <hip/hip_runtime.h>
#include <stdint.h>

typedef uint16_t u16;
typedef __attribute__((ext_vector_type(4))) float f32x4;
typedef __attribute__((ext_vector_type(8))) short bf16x8;

#define LOG2E 1.4426950408889634f

static __device__ __forceinline__ u16 f2b(float x){
  union { float f; uint32_t u; } a; a.f = x;
  uint32_t r = a.u + 0x7FFFu + ((a.u >> 16) & 1u);
  return (u16)(r >> 16);
}

#define GLD16(g, l) __builtin_amdgcn_global_load_lds((const __attribute__((address_space(1))) void*)(g), (__attribute__((address_space(3))) void*)(l), 16, 0, 0)

// ---------------- cast x: fp32 -> bf16 (8 elems/thread) ----------------
__global__ __launch_bounds__(256) void k_cast(const float* __restrict__ in, u16* __restrict__ out, int n8){
  int i = blockIdx.x * 256 + threadIdx.x;
  if (i >= n8) return;
  const f32x4* p = (const f32x4*)(in + (size_t)i * 8);
  f32x4 a = p[0], b = p[1];
  u16 h[8];
#pragma unroll
  for (int j = 0; j < 4; ++j){ h[j] = f2b(a[j]); h[4+j] = f2b(b[j]); }
  *(bf16x8*)(out + (size_t)i * 8) = *(const bf16x8*)h;
}

// ---------------- transpose-cast: W[R][C] fp32 -> Wt[C][R] bf16 ----------------
__global__ void k_tcast(const float* __restrict__ in, u16* __restrict__ out, int R, int C){
  __shared__ float t[32][33];
  int c0 = blockIdx.x * 32, r0 = blockIdx.y * 32;
  int tx = threadIdx.x, ty = threadIdx.y; // 32 x 8
#pragma unroll
  for (int i = 0; i < 32; i += 8) t[ty + i][tx] = in[(size_t)(r0 + ty + i) * C + c0 + tx];
  __syncthreads();
#pragma unroll
  for (int i = 0; i < 32; i += 8) out[(size_t)(c0 + ty + i) * R + r0 + tx] = f2b(t[tx][ty + i]);
}

// ---------------- m97-style GEMM: C[M,N] = A[M,768] * Bt[N,768]^T ----------------
// EPI 0: QKV epilogue (bf16 -> Q (x1/8), K, V-transposed); EPI 1: fp32 -> Co
template<int EPI>
__global__ __launch_bounds__(256) void k_gemm(const u16* __restrict__ A, const u16* __restrict__ Bt,
                                              u16* __restrict__ Qp, u16* __restrict__ Kp, u16* __restrict__ Vtp,
                                              float* __restrict__ Co){
  __shared__ __align__(16) u16 SM[16384]; // Al [128][64] | Bl [128][64]; reused as T[128][128] in V epilogue
  u16* Al = SM; u16* Bl = SM + 8192;
  const int tid = threadIdx.x;
  const int w = tid >> 6, l = tid & 63;
  const int m0 = blockIdx.x * 128, n0 = blockIdx.y * 128;
  const int wm = (w >> 1) * 64, wn = (w & 1) * 64;
  const int lg = l >> 4, lr = l & 15;
  f32x4 acc[4][4] = {};
  const u16* asrc = A  + (size_t)(m0 + w*32 + (l >> 3)) * 768 + (l & 7) * 8;
  const u16* bsrc = Bt + (size_t)(n0 + w*32 + (l >> 3)) * 768 + (l & 7) * 8;
  for (int k0 = 0; k0 < 768; k0 += 64){
#pragma unroll
    for (int i = 0; i < 4; ++i){
      GLD16(asrc + (size_t)(i*8)*768 + k0, &Al[(w*32 + i*8) * 64]);
      GLD16(bsrc + (size_t)(i*8)*768 + k0, &Bl[(w*32 + i*8) * 64]);
    }
    __syncthreads();
    bf16x8 af[4][2], bfr[4][2];
#pragma unroll
    for (int mf = 0; mf < 4; ++mf)
#pragma unroll
      for (int ks = 0; ks < 2; ++ks){
        af[mf][ks]  = *(const bf16x8*)&Al[(wm + mf*16 + lr) * 64 + ks*32 + lg*8];
        bfr[mf][ks] = *(const bf16x8*)&Bl[(wn + mf*16 + lr) * 64 + ks*32 + lg*8];
      }
#pragma unroll
    for (int ks = 0; ks < 2; ++ks)
#pragma unroll
      for (int mf = 0; mf < 4; ++mf)
#pragma unroll
        for (int nf = 0; nf < 4; ++nf)
          acc[mf][nf] = __builtin_amdgcn_mfma_f32_16x16x32_bf16(af[mf][ks], bfr[nf][ks], acc[mf][nf], 0, 0, 0);
    __syncthreads();
  }

  if (EPI == 1){
#pragma unroll
    for (int mf = 0; mf < 4; ++mf)
#pragma unroll
      for (int nf = 0; nf < 4; ++nf)
#pragma unroll
        for (int r = 0; r < 4; ++r)
          Co[(size_t)(m0 + wm + mf*16 + lg*4 + r) * 768 + n0 + wn + nf*16 + lr] = acc[mf][nf][r];
    return;
  }

  const int which = n0 / 768; // tiles never cross q/k/v boundary (768 % 128 == 0)
  if (which < 2){
    u16* dst = (which == 0) ? Qp : Kp;
    const float sc = (which == 0) ? 0.125f : 1.0f; // fold 1/sqrt(64) into Q
#pragma unroll
    for (int mf = 0; mf < 4; ++mf)
#pragma unroll
      for (int nf = 0; nf < 4; ++nf)
#pragma unroll
        for (int r = 0; r < 4; ++r){
          int m = m0 + wm + mf*16 + lg*4 + r;
          int n = (n0 - which*768) + wn + nf*16 + lr;
          int b = m >> 11, row = m & 2047, hh = n >> 6, d = n & 63;
          dst[(size_t)((b*12 + hh)*2048 + row) * 64 + d] = f2b(acc[mf][nf][r] * sc);
        }
  } else {
    // V tile: transpose through LDS, write Vt[b][h][d][key]
#pragma unroll
    for (int mf = 0; mf < 4; ++mf)
#pragma unroll
      for (int nf = 0; nf < 4; ++nf)
#pragma unroll
        for (int r = 0; r < 4; ++r){
          int mrow = wm + mf*16 + lg*4 + r;
          int c    = wn + nf*16 + lr;
          SM[c * 128 + mrow] = f2b(acc[mf][nf][r]);
        }
    __syncthreads();
#pragma unroll
    for (int rr = 0; rr < 8; ++rr){
      int c  = rr*16 + (tid >> 4);
      int mo = (tid & 15) * 8;
      bf16x8 v = *(const bf16x8*)&SM[c * 128 + mo];
      int n = (n0 - 1536) + c, hh = n >> 6, d = n & 63;
      int m = m0 + mo, b = m >> 11, key = m & 2047;
      *(bf16x8*)&Vtp[(size_t)((b*12 + hh)*64 + d) * 2048 + key] = v;
    }
  }
}

// ---------------- flash attention: 4 waves x 16 q-rows, KB=64 ----------------
__global__ __launch_bounds__(256) void k_attn(const u16* __restrict__ Qp, const u16* __restrict__ Kp,
                                              const u16* __restrict__ Vtp, u16* __restrict__ AO){
  __shared__ __align__(16) u16 Kl[64 * 72];      // [key][d], rows padded to 144B
  __shared__ __align__(16) u16 Vl[64 * 72];      // [d][key] (V^T), padded
  __shared__ __align__(16) u16 Pl[4][16 * 72];   // per-wave P [q][key], padded
  const int tid = threadIdx.x, w = tid >> 6, l = tid & 63;
  const int lg = l >> 4, lr = l & 15;
  const int qt = blockIdx.x, bh = blockIdx.y;
  const int b = bh / 12, h = bh - b * 12;
  const size_t base = (size_t)bh * (2048 * 64);
  const u16* Qg = Qp + base; const u16* Kg = Kp + base; const u16* Vg = Vtp + base;
  const int q0 = qt * 64 + w * 16;

  bf16x8 qf[2];
#pragma unroll
  for (int ks = 0; ks < 2; ++ks) qf[ks] = *(const bf16x8*)&Qg[(size_t)(q0 + lr) * 64 + ks*32 + lg*8];

  f32x4 oacc[4] = {};
  float mrow[4] = {-3e38f, -3e38f, -3e38f, -3e38f};
  float lrow[4] = {0.f, 0.f, 0.f, 0.f};
  const int srow = tid >> 3, soff = (tid & 7) * 8;

  for (int k0 = 0; k0 < 2048; k0 += 64){
#pragma unroll
    for (int rnd = 0; rnd < 2; ++rnd){
      int rw = rnd * 32 + srow;
      *(bf16x8*)&Kl[rw * 72 + soff] = *(const bf16x8*)&Kg[(size_t)(k0 + rw) * 64 + soff];
      *(bf16x8*)&Vl[rw * 72 + soff] = *(const bf16x8*)&Vg[((size_t)rw << 11) + k0 + soff];
    }
    __syncthreads();

    f32x4 s[4] = {};
#pragma unroll
    for (int ks = 0; ks < 2; ++ks)
#pragma unroll
      for (int kf = 0; kf < 4; ++kf){
        bf16x8 bk = *(const bf16x8*)&Kl[(kf*16 + lr) * 72 + ks*32 + lg*8];
        s[kf] = __builtin_amdgcn_mfma_f32_16x16x32_bf16(qf[ks], bk, s[kf], 0, 0, 0);
      }

    float fac[4];
#pragma unroll
    for (int r = 0; r < 4; ++r){
      float pm = fmaxf(fmaxf(s[0][r], s[1][r]), fmaxf(s[2][r], s[3][r]));
#pragma unroll
      for (int d = 1; d < 16; d <<= 1) pm = fmaxf(pm, __shfl_xor(pm, d));
      float mn = fmaxf(mrow[r], pm);
      fac[r] = exp2f((mrow[r] - mn) * LOG2E);
      mrow[r] = mn;
      float rs = 0.f;
#pragma unroll
      for (int kf = 0; kf < 4; ++kf){ float p = exp2f((s[kf][r] - mn) * LOG2E); s[kf][r] = p; rs += p; }
#pragma unroll
      for (int d = 1; d < 16; d <<= 1) rs += __shfl_xor(rs, d);
      lrow[r] = lrow[r] * fac[r] + rs;
    }
#pragma unroll
    for (int nf = 0; nf < 4; ++nf)
#pragma unroll
      for (int r = 0; r < 4; ++r) oacc[nf][r] *= fac[r];

#pragma unroll
    for (int kf = 0; kf < 4; ++kf)
#pragma unroll
      for (int r = 0; r < 4; ++r)
        Pl[w][(lg*4 + r) * 72 + kf*16 + lr] = f2b(s[kf][r]);

    bf16x8 pf[2];
#pragma unroll
    for (int ks = 0; ks < 2; ++ks) pf[ks] = *(const bf16x8*)&Pl[w][lr * 72 + ks*32 + lg*8];
#pragma unroll
    for (int ks = 0; ks < 2; ++ks)
#pragma unroll
      for (int nf = 0; nf < 4; ++nf){
        bf16x8 bv = *(const bf16x8*)&Vl[(nf*16 + lr) * 72 + ks*32 + lg*8];
        oacc[nf] = __builtin_amdgcn_mfma_f32_16x16x32_bf16(pf[ks], bv, oacc[nf], 0, 0, 0);
      }
    __syncthreads();
  }

#pragma unroll
  for (int r = 0; r < 4; ++r){
    float inv = 1.0f / lrow[r];
#pragma unroll
    for (int nf = 0; nf < 4; ++nf)
      AO[(size_t)((b << 11) + q0 + lg*4 + r) * 768 + h*64 + nf*16 + lr] = f2b(oacc[nf][r] * inv);
  }
}

extern "C" void kernel_launch(void* const* d_in, const int* in_sizes, int n_in,
                              void* d_out, int out_size, void* d_ws, size_t ws_size,
                              hipStream_t stream){
  const float* x      = (const float*)d_in[0];
  const float* w_qkv  = (const float*)d_in[1];
  const float* w_proj = (const float*)d_in[2];
  float* out = (float*)d_out;
  char* ws = (char*)d_ws;
  // workspace layout (all 256B-aligned)
  u16* Xb     = (u16*)(ws + 0);         // 4096x768 bf16   (6291456 B)
  u16* WqkvT  = (u16*)(ws + 6291456);   // 2304x768 bf16   (3538944 B)
  u16* WprojT = (u16*)(ws + 9830400);   // 768x768 bf16    (1179648 B)
  u16* Qp     = (u16*)(ws + 11010048);  // [2][12][2048][64] bf16 (6291456 B)
  u16* Kp     = (u16*)(ws + 17301504);
  u16* Vtp    = (u16*)(ws + 23592960);  // [2][12][64][2048] bf16
  u16* AO     = (u16*)(ws + 29884416);  // 4096x768 bf16

  k_cast<<<1536, 256, 0, stream>>>(x, Xb, 393216);
  k_tcast<<<dim3(72, 24), dim3(32, 8), 0, stream>>>(w_qkv, WqkvT, 768, 2304);
  k_tcast<<<dim3(24, 24), dim3(32, 8), 0, stream>>>(w_proj, WprojT, 768, 768);
  k_gemm<0><<<dim3(32, 18), 256, 0, stream>>>(Xb, WqkvT, Qp, Kp, Vtp, nullptr);
  k_attn<<<dim3(32, 24), 256, 0, stream>>>(Qp, Kp, Vtp, AO);
  k_gemm<1><<<dim3(32, 6), 256, 0, stream>>>(AO, WprojT, nullptr, nullptr, nullptr, out);
}

// Round 2
// 150.900 us; speedup vs baseline: 1.1412x; 1.1412x over previous
//
#include <hip/hip_runtime.h>
#include <hip/hip_bf16.h>
#include <stdint.h>

typedef uint16_t u16;
typedef __attribute__((ext_vector_type(4))) float f32x4;
typedef __attribute__((ext_vector_type(8))) short bf16x8;

#define LOG2E 1.4426950408889634f

static __device__ __forceinline__ u16 f2b(float x){
  union { float f; uint32_t u; } a; a.f = x;
  uint32_t r = a.u + 0x7FFFu + ((a.u >> 16) & 1u);
  return (u16)(r >> 16);
}

static __device__ __forceinline__ uint32_t pk2(float lo, float hi){
  __hip_bfloat162 t = __float22bfloat162_rn(float2{lo, hi});
  union { __hip_bfloat162 h; uint32_t u; } c; c.h = t; return c.u;
}

#define GLD16(g, l) __builtin_amdgcn_global_load_lds((const __attribute__((address_space(1))) void*)(g), (__attribute__((address_space(3))) void*)(l), 16, 0, 0)

// ---------------- cast x: fp32 -> bf16 (8 elems/thread) ----------------
__global__ __launch_bounds__(256) void k_cast(const float* __restrict__ in, u16* __restrict__ out, int n8){
  int i = blockIdx.x * 256 + threadIdx.x;
  if (i >= n8) return;
  const f32x4* p = (const f32x4*)(in + (size_t)i * 8);
  f32x4 a = p[0], b = p[1];
  u16 h[8];
#pragma unroll
  for (int j = 0; j < 4; ++j){ h[j] = f2b(a[j]); h[4+j] = f2b(b[j]); }
  *(bf16x8*)(out + (size_t)i * 8) = *(const bf16x8*)h;
}

// ---------------- transpose-cast: W[R][C] fp32 -> Wt[C][R] bf16 ----------------
__global__ void k_tcast(const float* __restrict__ in, u16* __restrict__ out, int R, int C){
  __shared__ float t[32][33];
  int c0 = blockIdx.x * 32, r0 = blockIdx.y * 32;
  int tx = threadIdx.x, ty = threadIdx.y; // 32 x 8
#pragma unroll
  for (int i = 0; i < 32; i += 8) t[ty + i][tx] = in[(size_t)(r0 + ty + i) * C + c0 + tx];
  __syncthreads();
#pragma unroll
  for (int i = 0; i < 32; i += 8) out[(size_t)(c0 + ty + i) * R + r0 + tx] = f2b(t[tx][ty + i]);
}

// ---------------- m97-style GEMM: C[M,N] = A[M,768] * Bt[N,768]^T ----------------
// EPI 0: QKV epilogue (bf16 -> Q (x LOG2E/8), K, V-transposed); EPI 1: fp32 -> Co
template<int EPI>
__global__ __launch_bounds__(256) void k_gemm(const u16* __restrict__ A, const u16* __restrict__ Bt,
                                              u16* __restrict__ Qp, u16* __restrict__ Kp, u16* __restrict__ Vtp,
                                              float* __restrict__ Co){
  __shared__ __align__(16) u16 SM[16384]; // Al [128][64] | Bl [128][64]; reused as T[128][128] in V epilogue
  u16* Al = SM; u16* Bl = SM + 8192;
  const int tid = threadIdx.x;
  const int w = tid >> 6, l = tid & 63;
  const int m0 = blockIdx.x * 128, n0 = blockIdx.y * 128;
  const int wm = (w >> 1) * 64, wn = (w & 1) * 64;
  const int lg = l >> 4, lr = l & 15;
  f32x4 acc[4][4] = {};
  const u16* asrc = A  + (size_t)(m0 + w*32 + (l >> 3)) * 768 + (l & 7) * 8;
  const u16* bsrc = Bt + (size_t)(n0 + w*32 + (l >> 3)) * 768 + (l & 7) * 8;
  for (int k0 = 0; k0 < 768; k0 += 64){
#pragma unroll
    for (int i = 0; i < 4; ++i){
      GLD16(asrc + (size_t)(i*8)*768 + k0, &Al[(w*32 + i*8) * 64]);
      GLD16(bsrc + (size_t)(i*8)*768 + k0, &Bl[(w*32 + i*8) * 64]);
    }
    __syncthreads();
    bf16x8 af[4][2], bfr[4][2];
#pragma unroll
    for (int mf = 0; mf < 4; ++mf)
#pragma unroll
      for (int ks = 0; ks < 2; ++ks){
        af[mf][ks]  = *(const bf16x8*)&Al[(wm + mf*16 + lr) * 64 + ks*32 + lg*8];
        bfr[mf][ks] = *(const bf16x8*)&Bl[(wn + mf*16 + lr) * 64 + ks*32 + lg*8];
      }
#pragma unroll
    for (int ks = 0; ks < 2; ++ks)
#pragma unroll
      for (int mf = 0; mf < 4; ++mf)
#pragma unroll
        for (int nf = 0; nf < 4; ++nf)
          acc[mf][nf] = __builtin_amdgcn_mfma_f32_16x16x32_bf16(af[mf][ks], bfr[nf][ks], acc[mf][nf], 0, 0, 0);
    __syncthreads();
  }

  if (EPI == 1){
#pragma unroll
    for (int mf = 0; mf < 4; ++mf)
#pragma unroll
      for (int nf = 0; nf < 4; ++nf)
#pragma unroll
        for (int r = 0; r < 4; ++r)
          Co[(size_t)(m0 + wm + mf*16 + lg*4 + r) * 768 + n0 + wn + nf*16 + lr] = acc[mf][nf][r];
    return;
  }

  const int which = n0 / 768; // tiles never cross q/k/v boundary (768 % 128 == 0)
  if (which < 2){
    u16* dst = (which == 0) ? Qp : Kp;
    const float sc = (which == 0) ? 0.125f * LOG2E : 1.0f; // fold 1/sqrt(64) AND log2(e) into Q
#pragma unroll
    for (int mf = 0; mf < 4; ++mf)
#pragma unroll
      for (int nf = 0; nf < 4; ++nf)
#pragma unroll
        for (int r = 0; r < 4; ++r){
          int m = m0 + wm + mf*16 + lg*4 + r;
          int n = (n0 - which*768) + wn + nf*16 + lr;
          int b = m >> 11, row = m & 2047, hh = n >> 6, d = n & 63;
          dst[(size_t)((b*12 + hh)*2048 + row) * 64 + d] = f2b(acc[mf][nf][r] * sc);
        }
  } else {
    // V tile: transpose through LDS, write Vt[b][h][d][key]
#pragma unroll
    for (int mf = 0; mf < 4; ++mf)
#pragma unroll
      for (int nf = 0; nf < 4; ++nf)
#pragma unroll
        for (int r = 0; r < 4; ++r){
          int mrow = wm + mf*16 + lg*4 + r;
          int c    = wn + nf*16 + lr;
          SM[c * 128 + mrow] = f2b(acc[mf][nf][r]);
        }
    __syncthreads();
#pragma unroll
    for (int rr = 0; rr < 8; ++rr){
      int c  = rr*16 + (tid >> 4);
      int mo = (tid & 15) * 8;
      bf16x8 v = *(const bf16x8*)&SM[c * 128 + mo];
      int n = (n0 - 1536) + c, hh = n >> 6, d = n & 63;
      int m = m0 + mo, b = m >> 11, key = m & 2047;
      *(bf16x8*)&Vtp[(size_t)((b*12 + hh)*64 + d) * 2048 + key] = v;
    }
  }
}

// ---------------- flash attention: swapped QK^T, lane-local softmax, defer-max ----------------
// 4 waves x 16 q-rows, KB=64. Q pre-scaled by log2(e)/8 -> softmax in exp2 domain.
__global__ __launch_bounds__(256) void k_attn(const u16* __restrict__ Qp, const u16* __restrict__ Kp,
                                              const u16* __restrict__ Vtp, u16* __restrict__ AO){
  __shared__ __align__(16) u16 Kl[64 * 72];      // [key][d], rows padded to 144B
  __shared__ __align__(16) u16 Vl[64 * 72];      // [d][key] (V^T), padded
  __shared__ __align__(16) u16 Pl[4][16 * 72];   // per-wave P [q][key] in A-frag layout, padded
  const int tid = threadIdx.x, w = tid >> 6, l = tid & 63;
  const int lg = l >> 4, lr = l & 15;
  const int qt = blockIdx.x, bh = blockIdx.y;
  const int b = bh / 12, h = bh - b * 12;
  const size_t base = (size_t)bh * (2048 * 64);
  const u16* Qg = Qp + base; const u16* Kg = Kp + base; const u16* Vg = Vtp + base;
  const int q0 = qt * 64 + w * 16;
  u16* Plw = &Pl[w][0];

  bf16x8 qf[2];
#pragma unroll
  for (int ks = 0; ks < 2; ++ks) qf[ks] = *(const bf16x8*)&Qg[(size_t)(q0 + lr) * 64 + ks*32 + lg*8];

  f32x4 oacc[4] = {};
  float m_r = -3e38f;    // running max for q = lr (replicated across the 4-lane lg group)
  float l_part = 0.f;    // this lane's partial sum over its own keys
  const int srow = tid >> 3, soff = (tid & 7) * 8;

  for (int k0 = 0; k0 < 2048; k0 += 64){
#pragma unroll
    for (int rnd = 0; rnd < 2; ++rnd){
      int rw = rnd * 32 + srow;
      *(bf16x8*)&Kl[rw * 72 + soff] = *(const bf16x8*)&Kg[(size_t)(k0 + rw) * 64 + soff];
      *(bf16x8*)&Vl[rw * 72 + soff] = *(const bf16x8*)&Vg[((size_t)rw << 11) + k0 + soff];
    }
    __syncthreads();

    // S^T = K * Q^T : lane (lg,lr) holds S[key = kf*16+lg*4+r][q = lr]
    f32x4 s[4] = {};
#pragma unroll
    for (int ks = 0; ks < 2; ++ks)
#pragma unroll
      for (int kf = 0; kf < 4; ++kf){
        bf16x8 bk = *(const bf16x8*)&Kl[(kf*16 + lr) * 72 + ks*32 + lg*8];
        s[kf] = __builtin_amdgcn_mfma_f32_16x16x32_bf16(bk, qf[ks], s[kf], 0, 0, 0);
      }

    // lane-local max over this lane's 16 scores
    float lm = fmaxf(fmaxf(fmaxf(s[0][0], s[0][1]), fmaxf(s[0][2], s[0][3])),
                     fmaxf(fmaxf(s[1][0], s[1][1]), fmaxf(s[1][2], s[1][3])));
    lm = fmaxf(lm, fmaxf(fmaxf(fmaxf(s[2][0], s[2][1]), fmaxf(s[2][2], s[2][3])),
                         fmaxf(fmaxf(s[3][0], s[3][1]), fmaxf(s[3][2], s[3][3]))));

    // defer-max: only rescale when some lane's tile-max exceeds running max + 8 (exp2 domain)
    if (!__all(lm <= m_r + 8.0f)){
      float mq = fmaxf(lm, __shfl_xor(lm, 16));
      mq = fmaxf(mq, __shfl_xor(mq, 32));            // true tile max for q=lr, replicated
      float nm = fmaxf(m_r, mq);
      float fac = exp2f(m_r - nm);
      m_r = nm;
      l_part *= fac;
#pragma unroll
      for (int r = 0; r < 4; ++r){
        float fo = __shfl(fac, lg*4 + r);            // fac for q = lg*4+r (O-domain row)
#pragma unroll
        for (int nf = 0; nf < 4; ++nf) oacc[nf][r] *= fo;
      }
    }

    // P = exp2(S - m), accumulate partial row-sums, pack pairs, write A-frag layout
#pragma unroll
    for (int kf = 0; kf < 4; ++kf){
      float p0 = __builtin_exp2f(s[kf][0] - m_r);
      float p1 = __builtin_exp2f(s[kf][1] - m_r);
      float p2 = __builtin_exp2f(s[kf][2] - m_r);
      float p3 = __builtin_exp2f(s[kf][3] - m_r);
      l_part += (p0 + p1) + (p2 + p3);
      uint2 dd; dd.x = pk2(p0, p1); dd.y = pk2(p2, p3);
      *(uint2*)&Plw[lr*72 + kf*16 + lg*4] = dd;      // keys kf*16+lg*4 .. +3 of row q=lr
    }

    bf16x8 pf[2];
#pragma unroll
    for (int ks = 0; ks < 2; ++ks) pf[ks] = *(const bf16x8*)&Plw[lr * 72 + ks*32 + lg*8];
#pragma unroll
    for (int ks = 0; ks < 2; ++ks)
#pragma unroll
      for (int nf = 0; nf < 4; ++nf){
        bf16x8 bv = *(const bf16x8*)&Vl[(nf*16 + lr) * 72 + ks*32 + lg*8];
        oacc[nf] = __builtin_amdgcn_mfma_f32_16x16x32_bf16(pf[ks], bv, oacc[nf], 0, 0, 0);
      }
    __syncthreads();
  }

  // final row-sum across the 4-lane group, then normalize + store
  float lt = l_part;
  lt += __shfl_xor(lt, 16);
  lt += __shfl_xor(lt, 32);
#pragma unroll
  for (int r = 0; r < 4; ++r){
    float li = __shfl(lt, lg*4 + r);                 // total sum for q = lg*4+r
    float inv = 1.0f / li;
#pragma unroll
    for (int nf = 0; nf < 4; ++nf)
      AO[(size_t)((b << 11) + q0 + lg*4 + r) * 768 + h*64 + nf*16 + lr] = f2b(oacc[nf][r] * inv);
  }
}

extern "C" void kernel_launch(void* const* d_in, const int* in_sizes, int n_in,
                              void* d_out, int out_size, void* d_ws, size_t ws_size,
                              hipStream_t stream){
  const float* x      = (const float*)d_in[0];
  const float* w_qkv  = (const float*)d_in[1];
  const float* w_proj = (const float*)d_in[2];
  float* out = (float*)d_out;
  char* ws = (char*)d_ws;
  // workspace layout (all 256B-aligned)
  u16* Xb     = (u16*)(ws + 0);         // 4096x768 bf16   (6291456 B)
  u16* WqkvT  = (u16*)(ws + 6291456);   // 2304x768 bf16   (3538944 B)
  u16* WprojT = (u16*)(ws + 9830400);   // 768x768 bf16    (1179648 B)
  u16* Qp     = (u16*)(ws + 11010048);  // [2][12][2048][64] bf16 (6291456 B)
  u16* Kp     = (u16*)(ws + 17301504);
  u16* Vtp    = (u16*)(ws + 23592960);  // [2][12][64][2048] bf16
  u16* AO     = (u16*)(ws + 29884416);  // 4096x768 bf16

  k_cast<<<1536, 256, 0, stream>>>(x, Xb, 393216);
  k_tcast<<<dim3(72, 24), dim3(32, 8), 0, stream>>>(w_qkv, WqkvT, 768, 2304);
  k_tcast<<<dim3(24, 24), dim3(32, 8), 0, stream>>>(w_proj, WprojT, 768, 768);
  k_gemm<0><<<dim3(32, 18), 256, 0, stream>>>(Xb, WqkvT, Qp, Kp, Vtp, nullptr);
  k_attn<<<dim3(32, 24), 256, 0, stream>>>(Qp, Kp, Vtp, AO);
  k_gemm<1><<<dim3(32, 6), 256, 0, stream>>>(AO, WprojT, nullptr, nullptr, nullptr, out);
}

// Round 3
// 137.231 us; speedup vs baseline: 1.2549x; 1.0996x over previous
//
#include <hip/hip_runtime.h>
#include <hip/hip_bf16.h>
#include <stdint.h>

typedef uint16_t u16;
typedef __attribute__((ext_vector_type(4))) float f32x4;
typedef __attribute__((ext_vector_type(8))) short bf16x8;

#define LOG2E 1.4426950408889634f

static __device__ __forceinline__ u16 f2b(float x){
  union { float f; uint32_t u; } a; a.f = x;
  uint32_t r = a.u + 0x7FFFu + ((a.u >> 16) & 1u);
  return (u16)(r >> 16);
}

static __device__ __forceinline__ uint32_t pk2(float lo, float hi){
  __hip_bfloat162 t = __float22bfloat162_rn(float2{lo, hi});
  union { __hip_bfloat162 h; uint32_t u; } c; c.h = t; return c.u;
}

#define GLD16(g, l) __builtin_amdgcn_global_load_lds((const __attribute__((address_space(1))) void*)(g), (__attribute__((address_space(3))) void*)(l), 16, 0, 0)

// ---------------- cast x: fp32 -> bf16 (8 elems/thread) ----------------
__global__ __launch_bounds__(256) void k_cast(const float* __restrict__ in, u16* __restrict__ out, int n8){
  int i = blockIdx.x * 256 + threadIdx.x;
  if (i >= n8) return;
  const f32x4* p = (const f32x4*)(in + (size_t)i * 8);
  f32x4 a = p[0], b = p[1];
  u16 h[8];
#pragma unroll
  for (int j = 0; j < 4; ++j){ h[j] = f2b(a[j]); h[4+j] = f2b(b[j]); }
  *(bf16x8*)(out + (size_t)i * 8) = *(const bf16x8*)h;
}

// ---------------- transpose-cast: W[R][C] fp32 -> Wt[C][R] bf16 ----------------
__global__ void k_tcast(const float* __restrict__ in, u16* __restrict__ out, int R, int C){
  __shared__ float t[32][33];
  int c0 = blockIdx.x * 32, r0 = blockIdx.y * 32;
  int tx = threadIdx.x, ty = threadIdx.y; // 32 x 8
#pragma unroll
  for (int i = 0; i < 32; i += 8) t[ty + i][tx] = in[(size_t)(r0 + ty + i) * C + c0 + tx];
  __syncthreads();
#pragma unroll
  for (int i = 0; i < 32; i += 8) out[(size_t)(c0 + ty + i) * R + r0 + tx] = f2b(t[tx][ty + i]);
}

// ---------------- m97-style GEMM: C[M,N] = A[M,768] * Bt[N,768]^T ----------------
template<int EPI>
__global__ __launch_bounds__(256) void k_gemm(const u16* __restrict__ A, const u16* __restrict__ Bt,
                                              u16* __restrict__ Qp, u16* __restrict__ Kp, u16* __restrict__ Vtp,
                                              float* __restrict__ Co){
  __shared__ __align__(16) u16 SM[16384];
  u16* Al = SM; u16* Bl = SM + 8192;
  const int tid = threadIdx.x;
  const int w = tid >> 6, l = tid & 63;
  const int m0 = blockIdx.x * 128, n0 = blockIdx.y * 128;
  const int wm = (w >> 1) * 64, wn = (w & 1) * 64;
  const int lg = l >> 4, lr = l & 15;
  f32x4 acc[4][4] = {};
  const u16* asrc = A  + (size_t)(m0 + w*32 + (l >> 3)) * 768 + (l & 7) * 8;
  const u16* bsrc = Bt + (size_t)(n0 + w*32 + (l >> 3)) * 768 + (l & 7) * 8;
  for (int k0 = 0; k0 < 768; k0 += 64){
#pragma unroll
    for (int i = 0; i < 4; ++i){
      GLD16(asrc + (size_t)(i*8)*768 + k0, &Al[(w*32 + i*8) * 64]);
      GLD16(bsrc + (size_t)(i*8)*768 + k0, &Bl[(w*32 + i*8) * 64]);
    }
    __syncthreads();
    bf16x8 af[4][2], bfr[4][2];
#pragma unroll
    for (int mf = 0; mf < 4; ++mf)
#pragma unroll
      for (int ks = 0; ks < 2; ++ks){
        af[mf][ks]  = *(const bf16x8*)&Al[(wm + mf*16 + lr) * 64 + ks*32 + lg*8];
        bfr[mf][ks] = *(const bf16x8*)&Bl[(wn + mf*16 + lr) * 64 + ks*32 + lg*8];
      }
#pragma unroll
    for (int ks = 0; ks < 2; ++ks)
#pragma unroll
      for (int mf = 0; mf < 4; ++mf)
#pragma unroll
        for (int nf = 0; nf < 4; ++nf)
          acc[mf][nf] = __builtin_amdgcn_mfma_f32_16x16x32_bf16(af[mf][ks], bfr[nf][ks], acc[mf][nf], 0, 0, 0);
    __syncthreads();
  }

  if (EPI == 1){
#pragma unroll
    for (int mf = 0; mf < 4; ++mf)
#pragma unroll
      for (int nf = 0; nf < 4; ++nf)
#pragma unroll
        for (int r = 0; r < 4; ++r)
          Co[(size_t)(m0 + wm + mf*16 + lg*4 + r) * 768 + n0 + wn + nf*16 + lr] = acc[mf][nf][r];
    return;
  }

  const int which = n0 / 768;
  if (which < 2){
    u16* dst = (which == 0) ? Qp : Kp;
    const float sc = (which == 0) ? 0.125f * LOG2E : 1.0f;
#pragma unroll
    for (int mf = 0; mf < 4; ++mf)
#pragma unroll
      for (int nf = 0; nf < 4; ++nf)
#pragma unroll
        for (int r = 0; r < 4; ++r){
          int m = m0 + wm + mf*16 + lg*4 + r;
          int n = (n0 - which*768) + wn + nf*16 + lr;
          int b = m >> 11, row = m & 2047, hh = n >> 6, d = n & 63;
          dst[(size_t)((b*12 + hh)*2048 + row) * 64 + d] = f2b(acc[mf][nf][r] * sc);
        }
  } else {
#pragma unroll
    for (int mf = 0; mf < 4; ++mf)
#pragma unroll
      for (int nf = 0; nf < 4; ++nf)
#pragma unroll
        for (int r = 0; r < 4; ++r){
          int mrow = wm + mf*16 + lg*4 + r;
          int c    = wn + nf*16 + lr;
          SM[c * 128 + mrow] = f2b(acc[mf][nf][r]);
        }
    __syncthreads();
#pragma unroll
    for (int rr = 0; rr < 8; ++rr){
      int c  = rr*16 + (tid >> 4);
      int mo = (tid & 15) * 8;
      bf16x8 v = *(const bf16x8*)&SM[c * 128 + mo];
      int n = (n0 - 1536) + c, hh = n >> 6, d = n & 63;
      int m = m0 + mo, b = m >> 11, key = m & 2047;
      *(bf16x8*)&Vtp[(size_t)((b*12 + hh)*64 + d) * 2048 + key] = v;
    }
  }
}

// ---------------- flash attention: async-staged double-buffered K/V ----------------
// 4 waves x 16 q-rows, KB=64. Q pre-scaled by log2(e)/8 -> exp2 domain.
// Per step: issue global loads(t+1) -> compute(t) from buf[c] -> write buf[c^1] -> ONE barrier.
__global__ __launch_bounds__(256) void k_attn(const u16* __restrict__ Qp, const u16* __restrict__ Kp,
                                              const u16* __restrict__ Vtp, u16* __restrict__ AO){
  __shared__ __align__(16) u16 Kl[2][64 * 72];   // [key][d], rows padded to 144B
  __shared__ __align__(16) u16 Vl[2][64 * 72];   // [d][key] (V^T), padded
  __shared__ __align__(16) u16 Pl[4][16 * 80];   // per-wave P, row stride 160B (conflict-free writes)
  const int tid = threadIdx.x, w = tid >> 6, l = tid & 63;
  const int lg = l >> 4, lr = l & 15;
  const int qt = blockIdx.x, bh = blockIdx.y;
  const int b = bh / 12, h = bh - b * 12;
  const size_t base = (size_t)bh * (2048 * 64);
  const u16* Qg = Qp + base; const u16* Kg = Kp + base; const u16* Vg = Vtp + base;
  const int q0 = qt * 64 + w * 16;
  u16* Plw = &Pl[w][0];

  bf16x8 qf[2];
#pragma unroll
  for (int ks = 0; ks < 2; ++ks) qf[ks] = *(const bf16x8*)&Qg[(size_t)(q0 + lr) * 64 + ks*32 + lg*8];

  f32x4 oacc[4] = {};
  float m_r = -3e38f;
  float l_part = 0.f;
  const int srow = tid >> 3, soff = (tid & 7) * 8;   // srow 0..31, soff 0..56

  // prologue: stage tile 0 into buf 0
  {
    bf16x8 kr0 = *(const bf16x8*)&Kg[(size_t)(srow) * 64 + soff];
    bf16x8 kr1 = *(const bf16x8*)&Kg[(size_t)(32 + srow) * 64 + soff];
    bf16x8 vr0 = *(const bf16x8*)&Vg[((size_t)srow << 11) + soff];
    bf16x8 vr1 = *(const bf16x8*)&Vg[((size_t)(32 + srow) << 11) + soff];
    *(bf16x8*)&Kl[0][srow * 72 + soff] = kr0;
    *(bf16x8*)&Kl[0][(32 + srow) * 72 + soff] = kr1;
    *(bf16x8*)&Vl[0][srow * 72 + soff] = vr0;
    *(bf16x8*)&Vl[0][(32 + srow) * 72 + soff] = vr1;
  }
  __syncthreads();
  int c = 0;

  for (int k0 = 0; k0 < 2048; k0 += 64){
    // issue next-tile global loads early (latency hides under compute)
    bf16x8 kr0, kr1, vr0, vr1;
    const bool hn = (k0 + 64) < 2048;
    if (hn){
      int kn = k0 + 64;
      kr0 = *(const bf16x8*)&Kg[(size_t)(kn + srow) * 64 + soff];
      kr1 = *(const bf16x8*)&Kg[(size_t)(kn + 32 + srow) * 64 + soff];
      vr0 = *(const bf16x8*)&Vg[((size_t)srow << 11) + kn + soff];
      vr1 = *(const bf16x8*)&Vg[((size_t)(32 + srow) << 11) + kn + soff];
    }

    const u16* Kc = &Kl[c][0];
    const u16* Vc = &Vl[c][0];

    // S^T = K * Q^T : lane (lg,lr) holds S[key = kf*16+lg*4+r][q = lr]
    f32x4 s[4] = {};
    __builtin_amdgcn_s_setprio(1);
#pragma unroll
    for (int ks = 0; ks < 2; ++ks)
#pragma unroll
      for (int kf = 0; kf < 4; ++kf){
        bf16x8 bk = *(const bf16x8*)&Kc[(kf*16 + lr) * 72 + ks*32 + lg*8];
        s[kf] = __builtin_amdgcn_mfma_f32_16x16x32_bf16(bk, qf[ks], s[kf], 0, 0, 0);
      }
    __builtin_amdgcn_s_setprio(0);

    float lm = fmaxf(fmaxf(fmaxf(s[0][0], s[0][1]), fmaxf(s[0][2], s[0][3])),
                     fmaxf(fmaxf(s[1][0], s[1][1]), fmaxf(s[1][2], s[1][3])));
    lm = fmaxf(lm, fmaxf(fmaxf(fmaxf(s[2][0], s[2][1]), fmaxf(s[2][2], s[2][3])),
                         fmaxf(fmaxf(s[3][0], s[3][1]), fmaxf(s[3][2], s[3][3]))));

    if (!__all(lm <= m_r + 8.0f)){
      float mq = fmaxf(lm, __shfl_xor(lm, 16));
      mq = fmaxf(mq, __shfl_xor(mq, 32));
      float nm = fmaxf(m_r, mq);
      float fac = exp2f(m_r - nm);
      m_r = nm;
      l_part *= fac;
#pragma unroll
      for (int r = 0; r < 4; ++r){
        float fo = __shfl(fac, lg*4 + r);
#pragma unroll
        for (int nf = 0; nf < 4; ++nf) oacc[nf][r] *= fo;
      }
    }

#pragma unroll
    for (int kf = 0; kf < 4; ++kf){
      float p0 = __builtin_exp2f(s[kf][0] - m_r);
      float p1 = __builtin_exp2f(s[kf][1] - m_r);
      float p2 = __builtin_exp2f(s[kf][2] - m_r);
      float p3 = __builtin_exp2f(s[kf][3] - m_r);
      l_part += (p0 + p1) + (p2 + p3);
      uint2 dd; dd.x = pk2(p0, p1); dd.y = pk2(p2, p3);
      *(uint2*)&Plw[lr*80 + kf*16 + lg*4] = dd;
    }

    bf16x8 pf[2];
#pragma unroll
    for (int ks = 0; ks < 2; ++ks) pf[ks] = *(const bf16x8*)&Plw[lr * 80 + ks*32 + lg*8];
    __builtin_amdgcn_s_setprio(1);
#pragma unroll
    for (int ks = 0; ks < 2; ++ks)
#pragma unroll
      for (int nf = 0; nf < 4; ++nf){
        bf16x8 bv = *(const bf16x8*)&Vc[(nf*16 + lr) * 72 + ks*32 + lg*8];
        oacc[nf] = __builtin_amdgcn_mfma_f32_16x16x32_bf16(pf[ks], bv, oacc[nf], 0, 0, 0);
      }
    __builtin_amdgcn_s_setprio(0);

    if (hn){
      int n = c ^ 1;
      *(bf16x8*)&Kl[n][srow * 72 + soff] = kr0;
      *(bf16x8*)&Kl[n][(32 + srow) * 72 + soff] = kr1;
      *(bf16x8*)&Vl[n][srow * 72 + soff] = vr0;
      *(bf16x8*)&Vl[n][(32 + srow) * 72 + soff] = vr1;
    }
    __syncthreads();
    c ^= 1;
  }

  float lt = l_part;
  lt += __shfl_xor(lt, 16);
  lt += __shfl_xor(lt, 32);
#pragma unroll
  for (int r = 0; r < 4; ++r){
    float li = __shfl(lt, lg*4 + r);
    float inv = 1.0f / li;
#pragma unroll
    for (int nf = 0; nf < 4; ++nf)
      AO[(size_t)((b << 11) + q0 + lg*4 + r) * 768 + h*64 + nf*16 + lr] = f2b(oacc[nf][r] * inv);
  }
}

extern "C" void kernel_launch(void* const* d_in, const int* in_sizes, int n_in,
                              void* d_out, int out_size, void* d_ws, size_t ws_size,
                              hipStream_t stream){
  const float* x      = (const float*)d_in[0];
  const float* w_qkv  = (const float*)d_in[1];
  const float* w_proj = (const float*)d_in[2];
  float* out = (float*)d_out;
  char* ws = (char*)d_ws;
  u16* Xb     = (u16*)(ws + 0);
  u16* WqkvT  = (u16*)(ws + 6291456);
  u16* WprojT = (u16*)(ws + 9830400);
  u16* Qp     = (u16*)(ws + 11010048);
  u16* Kp     = (u16*)(ws + 17301504);
  u16* Vtp    = (u16*)(ws + 23592960);
  u16* AO     = (u16*)(ws + 29884416);

  k_cast<<<1536, 256, 0, stream>>>(x, Xb, 393216);
  k_tcast<<<dim3(72, 24), dim3(32, 8), 0, stream>>>(w_qkv, WqkvT, 768, 2304);
  k_tcast<<<dim3(24, 24), dim3(32, 8), 0, stream>>>(w_proj, WprojT, 768, 768);
  k_gemm<0><<<dim3(32, 18), 256, 0, stream>>>(Xb, WqkvT, Qp, Kp, Vtp, nullptr);
  k_attn<<<dim3(32, 24), 256, 0, stream>>>(Qp, Kp, Vtp, AO);
  k_gemm<1><<<dim3(32, 6), 256, 0, stream>>>(AO, WprojT, nullptr, nullptr, nullptr, out);
}

// Round 4
// 132.512 us; speedup vs baseline: 1.2996x; 1.0356x over previous
//
#include <hip/hip_runtime.h>
#include <hip/hip_bf16.h>
#include <stdint.h>

typedef uint16_t u16;
typedef __attribute__((ext_vector_type(4))) float f32x4;
typedef __attribute__((ext_vector_type(8))) short bf16x8;

#define LOG2E 1.4426950408889634f

static __device__ __forceinline__ u16 f2b(float x){
  union { float f; uint32_t u; } a; a.f = x;
  uint32_t r = a.u + 0x7FFFu + ((a.u >> 16) & 1u);
  return (u16)(r >> 16);
}

static __device__ __forceinline__ uint32_t pk2(float lo, float hi){
  __hip_bfloat162 t = __float22bfloat162_rn(float2{lo, hi});
  union { __hip_bfloat162 h; uint32_t u; } c; c.h = t; return c.u;
}

#define GLD16(g, l) __builtin_amdgcn_global_load_lds((const __attribute__((address_space(1))) void*)(g), (__attribute__((address_space(3))) void*)(l), 16, 0, 0)

// ---------------- cast x: fp32 -> bf16 (8 elems/thread) ----------------
__global__ __launch_bounds__(256) void k_cast(const float* __restrict__ in, u16* __restrict__ out, int n8){
  int i = blockIdx.x * 256 + threadIdx.x;
  if (i >= n8) return;
  const f32x4* p = (const f32x4*)(in + (size_t)i * 8);
  f32x4 a = p[0], b = p[1];
  u16 h[8];
#pragma unroll
  for (int j = 0; j < 4; ++j){ h[j] = f2b(a[j]); h[4+j] = f2b(b[j]); }
  *(bf16x8*)(out + (size_t)i * 8) = *(const bf16x8*)h;
}

// ---------------- transpose-cast: W[R][C] fp32 -> Wt[C][R] bf16 ----------------
__global__ void k_tcast(const float* __restrict__ in, u16* __restrict__ out, int R, int C){
  __shared__ float t[32][33];
  int c0 = blockIdx.x * 32, r0 = blockIdx.y * 32;
  int tx = threadIdx.x, ty = threadIdx.y; // 32 x 8
#pragma unroll
  for (int i = 0; i < 32; i += 8) t[ty + i][tx] = in[(size_t)(r0 + ty + i) * C + c0 + tx];
  __syncthreads();
#pragma unroll
  for (int i = 0; i < 32; i += 8) out[(size_t)(c0 + ty + i) * R + r0 + tx] = f2b(t[tx][ty + i]);
}

// ---------------- m97-style GEMM: C[M,N] = A[M,768] * Bt[N,768]^T ----------------
template<int EPI>
__global__ __launch_bounds__(256) void k_gemm(const u16* __restrict__ A, const u16* __restrict__ Bt,
                                              u16* __restrict__ Qp, u16* __restrict__ Kp, u16* __restrict__ Vtp,
                                              float* __restrict__ Co){
  __shared__ __align__(16) u16 SM[16384];
  u16* Al = SM; u16* Bl = SM + 8192;
  const int tid = threadIdx.x;
  const int w = tid >> 6, l = tid & 63;
  const int m0 = blockIdx.x * 128, n0 = blockIdx.y * 128;
  const int wm = (w >> 1) * 64, wn = (w & 1) * 64;
  const int lg = l >> 4, lr = l & 15;
  f32x4 acc[4][4] = {};
  const u16* asrc = A  + (size_t)(m0 + w*32 + (l >> 3)) * 768 + (l & 7) * 8;
  const u16* bsrc = Bt + (size_t)(n0 + w*32 + (l >> 3)) * 768 + (l & 7) * 8;
  for (int k0 = 0; k0 < 768; k0 += 64){
#pragma unroll
    for (int i = 0; i < 4; ++i){
      GLD16(asrc + (size_t)(i*8)*768 + k0, &Al[(w*32 + i*8) * 64]);
      GLD16(bsrc + (size_t)(i*8)*768 + k0, &Bl[(w*32 + i*8) * 64]);
    }
    __syncthreads();
    bf16x8 af[4][2], bfr[4][2];
#pragma unroll
    for (int mf = 0; mf < 4; ++mf)
#pragma unroll
      for (int ks = 0; ks < 2; ++ks){
        af[mf][ks]  = *(const bf16x8*)&Al[(wm + mf*16 + lr) * 64 + ks*32 + lg*8];
        bfr[mf][ks] = *(const bf16x8*)&Bl[(wn + mf*16 + lr) * 64 + ks*32 + lg*8];
      }
#pragma unroll
    for (int ks = 0; ks < 2; ++ks)
#pragma unroll
      for (int mf = 0; mf < 4; ++mf)
#pragma unroll
        for (int nf = 0; nf < 4; ++nf)
          acc[mf][nf] = __builtin_amdgcn_mfma_f32_16x16x32_bf16(af[mf][ks], bfr[nf][ks], acc[mf][nf], 0, 0, 0);
    __syncthreads();
  }

  if (EPI == 1){
#pragma unroll
    for (int mf = 0; mf < 4; ++mf)
#pragma unroll
      for (int nf = 0; nf < 4; ++nf)
#pragma unroll
        for (int r = 0; r < 4; ++r)
          Co[(size_t)(m0 + wm + mf*16 + lg*4 + r) * 768 + n0 + wn + nf*16 + lr] = acc[mf][nf][r];
    return;
  }

  const int which = n0 / 768;
  if (which < 2){
    u16* dst = (which == 0) ? Qp : Kp;
    const float sc = (which == 0) ? 0.125f * LOG2E : 1.0f;
#pragma unroll
    for (int mf = 0; mf < 4; ++mf)
#pragma unroll
      for (int nf = 0; nf < 4; ++nf)
#pragma unroll
        for (int r = 0; r < 4; ++r){
          int m = m0 + wm + mf*16 + lg*4 + r;
          int n = (n0 - which*768) + wn + nf*16 + lr;
          int b = m >> 11, row = m & 2047, hh = n >> 6, d = n & 63;
          dst[(size_t)((b*12 + hh)*2048 + row) * 64 + d] = f2b(acc[mf][nf][r] * sc);
        }
  } else {
#pragma unroll
    for (int mf = 0; mf < 4; ++mf)
#pragma unroll
      for (int nf = 0; nf < 4; ++nf)
#pragma unroll
        for (int r = 0; r < 4; ++r){
          int mrow = wm + mf*16 + lg*4 + r;
          int c    = wn + nf*16 + lr;
          SM[c * 128 + mrow] = f2b(acc[mf][nf][r]);
        }
    __syncthreads();
#pragma unroll
    for (int rr = 0; rr < 8; ++rr){
      int c  = rr*16 + (tid >> 4);
      int mo = (tid & 15) * 8;
      bf16x8 v = *(const bf16x8*)&SM[c * 128 + mo];
      int n = (n0 - 1536) + c, hh = n >> 6, d = n & 63;
      int m = m0 + mo, b = m >> 11, key = m & 2047;
      *(bf16x8*)&Vtp[(size_t)((b*12 + hh)*64 + d) * 2048 + key] = v;
    }
  }
}

// ---------------- flash attention: GLD-direct double-buffered K/V, XOR-swizzled ----------------
// 4 waves x 16 q-rows, KB=64. Q pre-scaled by log2(e)/8 -> exp2 domain.
// LDS tiles are LINEAR [64][64] u16 (GLD16 requirement); swizzle is applied on the
// global SOURCE (col16 = (l&7)^(l>>3)) and on the READ (off ^ (lr&7)*8)  [T21].
__global__ __launch_bounds__(256) void k_attn(const u16* __restrict__ Qp, const u16* __restrict__ Kp,
                                              const u16* __restrict__ Vtp, u16* __restrict__ AO){
  __shared__ __align__(16) u16 Kl[2][64 * 64];   // [key][d], linear 128B rows
  __shared__ __align__(16) u16 Vl[2][64 * 64];   // [d][key] (V^T), linear
  __shared__ __align__(16) u16 Pl[4][16 * 80];   // per-wave P, row stride 160B
  const int tid = threadIdx.x, w = tid >> 6, l = tid & 63;
  const int lg = l >> 4, lr = l & 15;
  const int qt = blockIdx.x, bh = blockIdx.y;
  const int b = bh / 12, h = bh - b * 12;
  const size_t base = (size_t)bh * (2048 * 64);
  const u16* Qg = Qp + base; const u16* Kg = Kp + base; const u16* Vg = Vtp + base;
  const int q0 = qt * 64 + w * 16;
  u16* Plw = &Pl[w][0];

  bf16x8 qf[2];
#pragma unroll
  for (int ks = 0; ks < 2; ++ks) qf[ks] = *(const bf16x8*)&Qg[(size_t)(q0 + lr) * 64 + ks*32 + lg*8];

  f32x4 oacc[4] = {};
  float m_r = -3e38f;
  float l_part = 0.f;

  // staging geometry: wave w stages K rows [w*16, w*16+16) and V rows [w*16, w*16+16)
  // lane l -> row sub-offset (l>>3), phys col16 (l&7), fetches logical col16 (l&7)^(l>>3)
  const int r8  = l >> 3;
  const int csw = ((l & 7) ^ r8) << 3;                 // pre-swizzled u16 column offset
  const u16* kb0 = Kg + (size_t)(w*16 + r8) * 64 + csw;
  const u16* kb1 = kb0 + 8 * 64;
  const u16* vb0 = Vg + ((size_t)(w*16 + r8) << 11) + csw;
  const u16* vb1 = vb0 + ((size_t)8 << 11);
  // swizzled read offset helper: logical off (ks*32+lg*8) -> phys off ^ ((lr&7)*8)
  const int rsw = (lr & 7) * 8;

  // prologue: stage tile 0 into buf 0
  GLD16(kb0, &Kl[0][(w*16    ) * 64]);
  GLD16(kb1, &Kl[0][(w*16 + 8) * 64]);
  GLD16(vb0, &Vl[0][(w*16    ) * 64]);
  GLD16(vb1, &Vl[0][(w*16 + 8) * 64]);
  __syncthreads();
  int c = 0;

  for (int k0 = 0; k0 < 2048; k0 += 64){
    // issue next-tile GLDs into buf c^1 (latency hides under compute; barrier drains vmcnt)
    if (k0 + 64 < 2048){
      int kn = k0 + 64, n = c ^ 1;
      GLD16(kb0 + (size_t)kn * 64, &Kl[n][(w*16    ) * 64]);
      GLD16(kb1 + (size_t)kn * 64, &Kl[n][(w*16 + 8) * 64]);
      GLD16(vb0 + kn,              &Vl[n][(w*16    ) * 64]);
      GLD16(vb1 + kn,              &Vl[n][(w*16 + 8) * 64]);
    }

    const u16* Kc = &Kl[c][0];
    const u16* Vc = &Vl[c][0];

    // S^T = K * Q^T : lane (lg,lr) holds S[key = kf*16+lg*4+r][q = lr]
    f32x4 s[4] = {};
    __builtin_amdgcn_s_setprio(1);
#pragma unroll
    for (int ks = 0; ks < 2; ++ks)
#pragma unroll
      for (int kf = 0; kf < 4; ++kf){
        bf16x8 bk = *(const bf16x8*)&Kc[(kf*16 + lr) * 64 + ((ks*32 + lg*8) ^ rsw)];
        s[kf] = __builtin_amdgcn_mfma_f32_16x16x32_bf16(bk, qf[ks], s[kf], 0, 0, 0);
      }
    __builtin_amdgcn_s_setprio(0);

    // lane-local max via max3-shaped tree (clang fuses fmax(fmax(a,b),c) -> v_max3_f32)
    float t0 = fmaxf(fmaxf(s[0][0], s[0][1]), s[0][2]);
    float t1 = fmaxf(fmaxf(s[0][3], s[1][0]), s[1][1]);
    float t2 = fmaxf(fmaxf(s[1][2], s[1][3]), s[2][0]);
    float t3 = fmaxf(fmaxf(s[2][1], s[2][2]), s[2][3]);
    float t4 = fmaxf(fmaxf(s[3][0], s[3][1]), s[3][2]);
    float lm = fmaxf(fmaxf(fmaxf(t0, t1), t2), fmaxf(fmaxf(t3, t4), s[3][3]));

    if (!__all(lm <= m_r + 8.0f)){
      float mq = fmaxf(lm, __shfl_xor(lm, 16));
      mq = fmaxf(mq, __shfl_xor(mq, 32));
      float nm = fmaxf(m_r, mq);
      float fac = exp2f(m_r - nm);
      m_r = nm;
      l_part *= fac;
#pragma unroll
      for (int r = 0; r < 4; ++r){
        float fo = __shfl(fac, lg*4 + r);
#pragma unroll
        for (int nf = 0; nf < 4; ++nf) oacc[nf][r] *= fo;
      }
    }

#pragma unroll
    for (int kf = 0; kf < 4; ++kf){
      float p0 = __builtin_exp2f(s[kf][0] - m_r);
      float p1 = __builtin_exp2f(s[kf][1] - m_r);
      float p2 = __builtin_exp2f(s[kf][2] - m_r);
      float p3 = __builtin_exp2f(s[kf][3] - m_r);
      l_part += (p0 + p1) + (p2 + p3);
      uint2 dd; dd.x = pk2(p0, p1); dd.y = pk2(p2, p3);
      *(uint2*)&Plw[lr*80 + kf*16 + lg*4] = dd;
    }

    bf16x8 pf[2];
#pragma unroll
    for (int ks = 0; ks < 2; ++ks) pf[ks] = *(const bf16x8*)&Plw[lr * 80 + ks*32 + lg*8];
    __builtin_amdgcn_s_setprio(1);
#pragma unroll
    for (int ks = 0; ks < 2; ++ks)
#pragma unroll
      for (int nf = 0; nf < 4; ++nf){
        bf16x8 bv = *(const bf16x8*)&Vc[(nf*16 + lr) * 64 + ((ks*32 + lg*8) ^ rsw)];
        oacc[nf] = __builtin_amdgcn_mfma_f32_16x16x32_bf16(pf[ks], bv, oacc[nf], 0, 0, 0);
      }
    __builtin_amdgcn_s_setprio(0);

    __syncthreads();   // drains vmcnt -> buf c^1 is published for next step
    c ^= 1;
  }

  float lt = l_part;
  lt += __shfl_xor(lt, 16);
  lt += __shfl_xor(lt, 32);
#pragma unroll
  for (int r = 0; r < 4; ++r){
    float li = __shfl(lt, lg*4 + r);
    float inv = 1.0f / li;
#pragma unroll
    for (int nf = 0; nf < 4; ++nf)
      AO[(size_t)((b << 11) + q0 + lg*4 + r) * 768 + h*64 + nf*16 + lr] = f2b(oacc[nf][r] * inv);
  }
}

extern "C" void kernel_launch(void* const* d_in, const int* in_sizes, int n_in,
                              void* d_out, int out_size, void* d_ws, size_t ws_size,
                              hipStream_t stream){
  const float* x      = (const float*)d_in[0];
  const float* w_qkv  = (const float*)d_in[1];
  const float* w_proj = (const float*)d_in[2];
  float* out = (float*)d_out;
  char* ws = (char*)d_ws;
  u16* Xb     = (u16*)(ws + 0);
  u16* WqkvT  = (u16*)(ws + 6291456);
  u16* WprojT = (u16*)(ws + 9830400);
  u16* Qp     = (u16*)(ws + 11010048);
  u16* Kp     = (u16*)(ws + 17301504);
  u16* Vtp    = (u16*)(ws + 23592960);
  u16* AO     = (u16*)(ws + 29884416);

  k_cast<<<1536, 256, 0, stream>>>(x, Xb, 393216);
  k_tcast<<<dim3(72, 24), dim3(32, 8), 0, stream>>>(w_qkv, WqkvT, 768, 2304);
  k_tcast<<<dim3(24, 24), dim3(32, 8), 0, stream>>>(w_proj, WprojT, 768, 768);
  k_gemm<0><<<dim3(32, 18), 256, 0, stream>>>(Xb, WqkvT, Qp, Kp, Vtp, nullptr);
  k_attn<<<dim3(32, 24), 256, 0, stream>>>(Qp, Kp, Vtp, AO);
  k_gemm<1><<<dim3(32, 6), 256, 0, stream>>>(AO, WprojT, nullptr, nullptr, nullptr, out);
}

// Round 5
// 113.515 us; speedup vs baseline: 1.5171x; 1.1674x over previous
//
#include <hip/hip_runtime.h>
#include <hip/hip_bf16.h>
#include <stdint.h>

typedef uint16_t u16;
typedef __attribute__((ext_vector_type(4))) float f32x4;
typedef __attribute__((ext_vector_type(8))) short bf16x8;

#define LOG2E 1.4426950408889634f

static __device__ __forceinline__ u16 f2b(float x){
  union { float f; uint32_t u; } a; a.f = x;
  uint32_t r = a.u + 0x7FFFu + ((a.u >> 16) & 1u);
  return (u16)(r >> 16);
}

// pack two f32 -> two bf16 (round-half-up) in 3 VALU: add, add, v_perm_b32
static __device__ __forceinline__ uint32_t pkrhu(float lo, float hi){
  union { float f; uint32_t u; } a, b; a.f = lo; b.f = hi;
  return __builtin_amdgcn_perm(b.u + 0x8000u, a.u + 0x8000u, 0x07060302u);
}

#define GLD16(g, l) __builtin_amdgcn_global_load_lds((const __attribute__((address_space(1))) void*)(g), (__attribute__((address_space(3))) void*)(l), 16, 0, 0)

// ---------------- cast x: fp32 -> bf16 (8 elems/thread) ----------------
__global__ __launch_bounds__(256) void k_cast(const float* __restrict__ in, u16* __restrict__ out, int n8){
  int i = blockIdx.x * 256 + threadIdx.x;
  if (i >= n8) return;
  const f32x4* p = (const f32x4*)(in + (size_t)i * 8);
  f32x4 a = p[0], b = p[1];
  u16 h[8];
#pragma unroll
  for (int j = 0; j < 4; ++j){ h[j] = f2b(a[j]); h[4+j] = f2b(b[j]); }
  *(bf16x8*)(out + (size_t)i * 8) = *(const bf16x8*)h;
}

// ---------------- transpose-cast: W[R][C] fp32 -> Wt[C][R] bf16 ----------------
__global__ void k_tcast(const float* __restrict__ in, u16* __restrict__ out, int R, int C){
  __shared__ float t[32][33];
  int c0 = blockIdx.x * 32, r0 = blockIdx.y * 32;
  int tx = threadIdx.x, ty = threadIdx.y; // 32 x 8
#pragma unroll
  for (int i = 0; i < 32; i += 8) t[ty + i][tx] = in[(size_t)(r0 + ty + i) * C + c0 + tx];
  __syncthreads();
#pragma unroll
  for (int i = 0; i < 32; i += 8) out[(size_t)(c0 + ty + i) * R + r0 + tx] = f2b(t[tx][ty + i]);
}

// ---------------- QKV GEMM: 128x96 tile, grid 32x24 = 768 blocks (3.0/CU) ----------------
// C[M,2304] = A[M,768] * Bt[2304,768]^T ; epilogue scatters Q(x LOG2E/8), K, V-transposed.
__global__ __launch_bounds__(256) void k_gemmqkv(const u16* __restrict__ A, const u16* __restrict__ Bt,
                                                 u16* __restrict__ Qp, u16* __restrict__ Kp, u16* __restrict__ Vtp){
  __shared__ __align__(16) u16 SM[14336];  // Al 128x64 (8192) | Bl 96x64 (6144); V-epi reuse 96x128 (12288)
  u16* Al = SM; u16* Bl = SM + 8192;
  const int tid = threadIdx.x;
  const int w = tid >> 6, l = tid & 63;
  const int m0 = blockIdx.x * 128, n0 = blockIdx.y * 96;
  const int wm = (w >> 1) * 64, wn = (w & 1) * 48;
  const int lg = l >> 4, lr = l & 15;
  f32x4 acc[4][3] = {};
  const u16* asrc = A  + (size_t)(m0 + w*32 + (l >> 3)) * 768 + (l & 7) * 8;
  const u16* bsrc = Bt + (size_t)(n0 + w*24 + (l >> 3)) * 768 + (l & 7) * 8;
  for (int k0 = 0; k0 < 768; k0 += 64){
#pragma unroll
    for (int i = 0; i < 4; ++i)
      GLD16(asrc + (size_t)(i*8)*768 + k0, &Al[(w*32 + i*8) * 64]);
#pragma unroll
    for (int i = 0; i < 3; ++i)
      GLD16(bsrc + (size_t)(i*8)*768 + k0, &Bl[(w*24 + i*8) * 64]);
    __syncthreads();
    bf16x8 af[4][2], bfr[3][2];
#pragma unroll
    for (int mf = 0; mf < 4; ++mf)
#pragma unroll
      for (int ks = 0; ks < 2; ++ks)
        af[mf][ks] = *(const bf16x8*)&Al[(wm + mf*16 + lr) * 64 + ks*32 + lg*8];
#pragma unroll
    for (int nf = 0; nf < 3; ++nf)
#pragma unroll
      for (int ks = 0; ks < 2; ++ks)
        bfr[nf][ks] = *(const bf16x8*)&Bl[(wn + nf*16 + lr) * 64 + ks*32 + lg*8];
#pragma unroll
    for (int ks = 0; ks < 2; ++ks)
#pragma unroll
      for (int mf = 0; mf < 4; ++mf)
#pragma unroll
        for (int nf = 0; nf < 3; ++nf)
          acc[mf][nf] = __builtin_amdgcn_mfma_f32_16x16x32_bf16(af[mf][ks], bfr[nf][ks], acc[mf][nf], 0, 0, 0);
    __syncthreads();
  }

  const int which = n0 / 768;            // 768 % 96 == 0 -> tiles never cross q/k/v boundary
  const int nl0 = n0 - which * 768;
  if (which < 2){
    u16* dst = (which == 0) ? Qp : Kp;
    const float sc = (which == 0) ? 0.125f * LOG2E : 1.0f;
#pragma unroll
    for (int mf = 0; mf < 4; ++mf)
#pragma unroll
      for (int nf = 0; nf < 3; ++nf)
#pragma unroll
        for (int r = 0; r < 4; ++r){
          int m = m0 + wm + mf*16 + lg*4 + r;
          int n = nl0 + wn + nf*16 + lr;
          int b = m >> 11, row = m & 2047, hh = n >> 6, d = n & 63;
          dst[(size_t)((b*12 + hh)*2048 + row) * 64 + d] = f2b(acc[mf][nf][r] * sc);
        }
  } else {
    // V tile: transpose through LDS, write Vt[b][h][d][key]
#pragma unroll
    for (int mf = 0; mf < 4; ++mf)
#pragma unroll
      for (int nf = 0; nf < 3; ++nf)
#pragma unroll
        for (int r = 0; r < 4; ++r){
          int mrow = wm + mf*16 + lg*4 + r;
          int c    = wn + nf*16 + lr;
          SM[c * 128 + mrow] = f2b(acc[mf][nf][r]);
        }
    __syncthreads();
#pragma unroll
    for (int rr = 0; rr < 6; ++rr){
      int c  = rr*16 + (tid >> 4);
      int mo = (tid & 15) * 8;
      bf16x8 v = *(const bf16x8*)&SM[c * 128 + mo];
      int n = nl0 + c, hh = n >> 6, d = n & 63;
      int m = m0 + mo, b = m >> 11, key = m & 2047;
      *(bf16x8*)&Vtp[(size_t)((b*12 + hh)*64 + d) * 2048 + key] = v;
    }
  }
}

// ---------------- proj GEMM: 64x64 tile, grid 64x12 = 768 blocks (3.0/CU) ----------------
__global__ __launch_bounds__(256) void k_gemm64(const u16* __restrict__ A, const u16* __restrict__ Bt,
                                                float* __restrict__ Co){
  __shared__ __align__(16) u16 SM[8192];  // Al 64x64 | Bl 64x64
  u16* Al = SM; u16* Bl = SM + 4096;
  const int tid = threadIdx.x;
  const int w = tid >> 6, l = tid & 63;
  const int m0 = blockIdx.x * 64, n0 = blockIdx.y * 64;
  const int wm = (w >> 1) * 32, wn = (w & 1) * 32;
  const int lg = l >> 4, lr = l & 15;
  f32x4 acc[2][2] = {};
  const u16* asrc = A  + (size_t)(m0 + w*16 + (l >> 3)) * 768 + (l & 7) * 8;
  const u16* bsrc = Bt + (size_t)(n0 + w*16 + (l >> 3)) * 768 + (l & 7) * 8;
  for (int k0 = 0; k0 < 768; k0 += 64){
#pragma unroll
    for (int i = 0; i < 2; ++i){
      GLD16(asrc + (size_t)(i*8)*768 + k0, &Al[(w*16 + i*8) * 64]);
      GLD16(bsrc + (size_t)(i*8)*768 + k0, &Bl[(w*16 + i*8) * 64]);
    }
    __syncthreads();
    bf16x8 af[2][2], bfr[2][2];
#pragma unroll
    for (int mf = 0; mf < 2; ++mf)
#pragma unroll
      for (int ks = 0; ks < 2; ++ks){
        af[mf][ks]  = *(const bf16x8*)&Al[(wm + mf*16 + lr) * 64 + ks*32 + lg*8];
        bfr[mf][ks] = *(const bf16x8*)&Bl[(wn + mf*16 + lr) * 64 + ks*32 + lg*8];
      }
#pragma unroll
    for (int ks = 0; ks < 2; ++ks)
#pragma unroll
      for (int mf = 0; mf < 2; ++mf)
#pragma unroll
        for (int nf = 0; nf < 2; ++nf)
          acc[mf][nf] = __builtin_amdgcn_mfma_f32_16x16x32_bf16(af[mf][ks], bfr[nf][ks], acc[mf][nf], 0, 0, 0);
    __syncthreads();
  }
#pragma unroll
  for (int mf = 0; mf < 2; ++mf)
#pragma unroll
    for (int nf = 0; nf < 2; ++nf)
#pragma unroll
      for (int r = 0; r < 4; ++r)
        Co[(size_t)(m0 + wm + mf*16 + lg*4 + r) * 768 + n0 + wn + nf*16 + lr] = acc[mf][nf][r];
}

// ---------------- flash attention: GLD-direct double-buffered K/V, XOR-swizzled ----------------
// 4 waves x 16 q-rows, KB=64. Q pre-scaled by log2(e)/8 -> exp2 domain.
__global__ __launch_bounds__(256) void k_attn(const u16* __restrict__ Qp, const u16* __restrict__ Kp,
                                              const u16* __restrict__ Vtp, u16* __restrict__ AO){
  __shared__ __align__(16) u16 Kl[2][64 * 64];   // [key][d], linear 128B rows
  __shared__ __align__(16) u16 Vl[2][64 * 64];   // [d][key] (V^T), linear
  __shared__ __align__(16) u16 Pl[4][16 * 80];   // per-wave P, row stride 160B
  const int tid = threadIdx.x, w = tid >> 6, l = tid & 63;
  const int lg = l >> 4, lr = l & 15;
  const int qt = blockIdx.x, bh = blockIdx.y;
  const int b = bh / 12, h = bh - b * 12;
  const size_t base = (size_t)bh * (2048 * 64);
  const u16* Qg = Qp + base; const u16* Kg = Kp + base; const u16* Vg = Vtp + base;
  const int q0 = qt * 64 + w * 16;
  u16* Plw = &Pl[w][0];

  bf16x8 qf[2];
#pragma unroll
  for (int ks = 0; ks < 2; ++ks) qf[ks] = *(const bf16x8*)&Qg[(size_t)(q0 + lr) * 64 + ks*32 + lg*8];

  f32x4 oacc[4] = {};
  float m_r = -3e38f;
  float l_part = 0.f;

  // staging: lane l -> row sub (l>>3), phys col16 (l&7) holds logical col16 (l&7)^(l>>3)  [T21]
  const int r8  = l >> 3;
  const int csw = ((l & 7) ^ r8) << 3;
  const u16* kb0 = Kg + (size_t)(w*16 + r8) * 64 + csw;
  const u16* kb1 = kb0 + 8 * 64;
  const u16* vb0 = Vg + ((size_t)(w*16 + r8) << 11) + csw;
  const u16* vb1 = vb0 + ((size_t)8 << 11);
  const int rsw = (lr & 7) * 8;     // read-side XOR

  GLD16(kb0, &Kl[0][(w*16    ) * 64]);
  GLD16(kb1, &Kl[0][(w*16 + 8) * 64]);
  GLD16(vb0, &Vl[0][(w*16    ) * 64]);
  GLD16(vb1, &Vl[0][(w*16 + 8) * 64]);
  __syncthreads();
  int c = 0;

  for (int k0 = 0; k0 < 2048; k0 += 64){
    if (k0 + 64 < 2048){
      int kn = k0 + 64, n = c ^ 1;
      GLD16(kb0 + (size_t)kn * 64, &Kl[n][(w*16    ) * 64]);
      GLD16(kb1 + (size_t)kn * 64, &Kl[n][(w*16 + 8) * 64]);
      GLD16(vb0 + kn,              &Vl[n][(w*16    ) * 64]);
      GLD16(vb1 + kn,              &Vl[n][(w*16 + 8) * 64]);
    }

    const u16* Kc = &Kl[c][0];
    const u16* Vc = &Vl[c][0];

    // S^T = K * Q^T : lane (lg,lr) holds S[key = kf*16+lg*4+r][q = lr]
    f32x4 s[4] = {};
    __builtin_amdgcn_s_setprio(1);
#pragma unroll
    for (int ks = 0; ks < 2; ++ks)
#pragma unroll
      for (int kf = 0; kf < 4; ++kf){
        bf16x8 bk = *(const bf16x8*)&Kc[(kf*16 + lr) * 64 + ((ks*32 + lg*8) ^ rsw)];
        s[kf] = __builtin_amdgcn_mfma_f32_16x16x32_bf16(bk, qf[ks], s[kf], 0, 0, 0);
      }
    __builtin_amdgcn_s_setprio(0);

    float t0 = fmaxf(fmaxf(s[0][0], s[0][1]), s[0][2]);
    float t1 = fmaxf(fmaxf(s[0][3], s[1][0]), s[1][1]);
    float t2 = fmaxf(fmaxf(s[1][2], s[1][3]), s[2][0]);
    float t3 = fmaxf(fmaxf(s[2][1], s[2][2]), s[2][3]);
    float t4 = fmaxf(fmaxf(s[3][0], s[3][1]), s[3][2]);
    float lm = fmaxf(fmaxf(fmaxf(t0, t1), t2), fmaxf(fmaxf(t3, t4), s[3][3]));

    if (!__all(lm <= m_r + 8.0f)){
      float mq = fmaxf(lm, __shfl_xor(lm, 16));
      mq = fmaxf(mq, __shfl_xor(mq, 32));
      float nm = fmaxf(m_r, mq);
      float fac = exp2f(m_r - nm);
      m_r = nm;
      l_part *= fac;
#pragma unroll
      for (int r = 0; r < 4; ++r){
        float fo = __shfl(fac, lg*4 + r);
#pragma unroll
        for (int nf = 0; nf < 4; ++nf) oacc[nf][r] *= fo;
      }
    }

#pragma unroll
    for (int kf = 0; kf < 4; ++kf){
      float p0 = __builtin_exp2f(s[kf][0] - m_r);
      float p1 = __builtin_exp2f(s[kf][1] - m_r);
      float p2 = __builtin_exp2f(s[kf][2] - m_r);
      float p3 = __builtin_exp2f(s[kf][3] - m_r);
      l_part += (p0 + p1) + (p2 + p3);
      uint2 dd; dd.x = pkrhu(p0, p1); dd.y = pkrhu(p2, p3);
      *(uint2*)&Plw[lr*80 + kf*16 + lg*4] = dd;
    }

    bf16x8 pf[2];
#pragma unroll
    for (int ks = 0; ks < 2; ++ks) pf[ks] = *(const bf16x8*)&Plw[lr * 80 + ks*32 + lg*8];
    __builtin_amdgcn_s_setprio(1);
#pragma unroll
    for (int ks = 0; ks < 2; ++ks)
#pragma unroll
      for (int nf = 0; nf < 4; ++nf){
        bf16x8 bv = *(const bf16x8*)&Vc[(nf*16 + lr) * 64 + ((ks*32 + lg*8) ^ rsw)];
        oacc[nf] = __builtin_amdgcn_mfma_f32_16x16x32_bf16(pf[ks], bv, oacc[nf], 0, 0, 0);
      }
    __builtin_amdgcn_s_setprio(0);

    __syncthreads();
    c ^= 1;
  }

  float lt = l_part;
  lt += __shfl_xor(lt, 16);
  lt += __shfl_xor(lt, 32);
#pragma unroll
  for (int r = 0; r < 4; ++r){
    float li = __shfl(lt, lg*4 + r);
    float inv = 1.0f / li;
#pragma unroll
    for (int nf = 0; nf < 4; ++nf)
      AO[(size_t)((b << 11) + q0 + lg*4 + r) * 768 + h*64 + nf*16 + lr] = f2b(oacc[nf][r] * inv);
  }
}

extern "C" void kernel_launch(void* const* d_in, const int* in_sizes, int n_in,
                              void* d_out, int out_size, void* d_ws, size_t ws_size,
                              hipStream_t stream){
  const float* x      = (const float*)d_in[0];
  const float* w_qkv  = (const float*)d_in[1];
  const float* w_proj = (const float*)d_in[2];
  float* out = (float*)d_out;
  char* ws = (char*)d_ws;
  u16* Xb     = (u16*)(ws + 0);
  u16* WqkvT  = (u16*)(ws + 6291456);
  u16* WprojT = (u16*)(ws + 9830400);
  u16* Qp     = (u16*)(ws + 11010048);
  u16* Kp     = (u16*)(ws + 17301504);
  u16* Vtp    = (u16*)(ws + 23592960);
  u16* AO     = (u16*)(ws + 29884416);

  k_cast<<<1536, 256, 0, stream>>>(x, Xb, 393216);
  k_tcast<<<dim3(72, 24), dim3(32, 8), 0, stream>>>(w_qkv, WqkvT, 768, 2304);
  k_tcast<<<dim3(24, 24), dim3(32, 8), 0, stream>>>(w_proj, WprojT, 768, 768);
  k_gemmqkv<<<dim3(32, 24), 256, 0, stream>>>(Xb, WqkvT, Qp, Kp, Vtp);
  k_attn<<<dim3(32, 24), 256, 0, stream>>>(Qp, Kp, Vtp, AO);
  k_gemm64<<<dim3(64, 12), 256, 0, stream>>>(AO, WprojT, out);
}